// Round 1
// baseline (1362.535 us; speedup 1.0000x reference)
//
#include <hip/hip_runtime.h>
#include <hip/hip_bf16.h>
#include <type_traits>
#include <cmath>

// ---- problem constants ----
#define HIDDEN 4096
#define NHEADS 32
#define NKV 8
#define HD 128
#define BB 2
#define SS 2048
#define NTOK (BB*SS)                  // 4096 tokens
#define ATTN_MULT 0.08838834764831845f

using bf16x8 = __attribute__((ext_vector_type(8))) short;
using f32x4  = __attribute__((ext_vector_type(4))) float;

using gas = __attribute__((address_space(1))) const void;
using las = __attribute__((address_space(3))) void;

__device__ __forceinline__ unsigned short f2bf(float f){
  unsigned int u = __builtin_bit_cast(unsigned int, f);
  u += 0x7fffu + ((u >> 16) & 1u);
  return (unsigned short)(u >> 16);
}
__device__ __forceinline__ float bf2f(unsigned short b){
  unsigned int u = ((unsigned int)b) << 16;
  return __builtin_bit_cast(float, u);
}

// ---- fp32 -> bf16 elementwise (8 el/thread) ----
__global__ void cvt_f32_bf16_k(const float* __restrict__ in, unsigned short* __restrict__ out, int n8){
  int i = blockIdx.x * blockDim.x + threadIdx.x;
  if (i >= n8) return;
  const float4* p = (const float4*)in + (size_t)i * 2;
  float4 a = p[0], b = p[1];
  bf16x8 o;
  o[0]=f2bf(a.x); o[1]=f2bf(a.y); o[2]=f2bf(a.z); o[3]=f2bf(a.w);
  o[4]=f2bf(b.x); o[5]=f2bf(b.y); o[6]=f2bf(b.z); o[7]=f2bf(b.w);
  ((bf16x8*)out)[i] = o;
}

// ---- W[K][N] fp32 -> WT[N][K] bf16 (tiled transpose) ----
__global__ void transpose_cvt_k(const float* __restrict__ W, unsigned short* __restrict__ WT, int K, int N){
  __shared__ float tile[32][33];
  int n0 = blockIdx.x * 32, k0 = blockIdx.y * 32;
  int tx = threadIdx.x, ty = threadIdx.y; // 32 x 8
  #pragma unroll
  for (int i = 0; i < 4; ++i)
    tile[ty*4+i][tx] = W[(size_t)(k0 + ty*4 + i) * N + n0 + tx];
  __syncthreads();
  #pragma unroll
  for (int i = 0; i < 4; ++i)
    WT[(size_t)(n0 + ty*4 + i) * K + k0 + tx] = f2bf(tile[tx][ty*4+i]);
}

// ---- bf16 GEMM: C[M][N] = A[M][K] * BT[N][K]^T, m97-style 128x128x32 ----
template<typename OutT>
__global__ void gemm_bt_k(const unsigned short* __restrict__ A,
                          const unsigned short* __restrict__ BT,
                          OutT* __restrict__ C, int M, int N, int K){
  __shared__ __align__(16) unsigned short As[128*32];
  __shared__ __align__(16) unsigned short Bs[128*32];
  const int m0 = blockIdx.y * 128, n0 = blockIdx.x * 128;
  const int tid = threadIdx.x, w = tid >> 6, lane = tid & 63;
  const int wr = w >> 1, wc = w & 1;
  const int lrow = lane & 15, lk = (lane >> 4) * 8;
  const int arow = lane >> 2, acol = (lane & 3) * 8;   // staging: lane covers 8 el

  f32x4 acc[4][4] = {};

  for (int k0 = 0; k0 < K; k0 += 32){
    #pragma unroll
    for (int i = 0; i < 2; ++i){
      int chunk = w*2 + i;  // 0..7, each 512 el (16 rows x 32 k)
      const unsigned short* ga = A  + (size_t)(m0 + chunk*16 + arow) * K + k0 + acol;
      const unsigned short* gb = BT + (size_t)(n0 + chunk*16 + arow) * K + k0 + acol;
      __builtin_amdgcn_global_load_lds((gas*)ga, (las*)(As + chunk*512), 16, 0, 0);
      __builtin_amdgcn_global_load_lds((gas*)gb, (las*)(Bs + chunk*512), 16, 0, 0);
    }
    __syncthreads();
    bf16x8 af[4], bfr[4];
    #pragma unroll
    for (int m = 0; m < 4; ++m) af[m]  = *(const bf16x8*)&As[(wr*64 + m*16 + lrow)*32 + lk];
    #pragma unroll
    for (int n = 0; n < 4; ++n) bfr[n] = *(const bf16x8*)&Bs[(wc*64 + n*16 + lrow)*32 + lk];
    #pragma unroll
    for (int m = 0; m < 4; ++m)
      #pragma unroll
      for (int n = 0; n < 4; ++n)
        acc[m][n] = __builtin_amdgcn_mfma_f32_16x16x32_bf16(af[m], bfr[n], acc[m][n], 0, 0, 0);
    __syncthreads();
  }

  const int crow = (lane >> 4) * 4, ccol = lane & 15;
  #pragma unroll
  for (int m = 0; m < 4; ++m)
    #pragma unroll
    for (int n = 0; n < 4; ++n){
      size_t base = (size_t)(m0 + wr*64 + m*16 + crow) * N + n0 + wc*64 + n*16 + ccol;
      #pragma unroll
      for (int r = 0; r < 4; ++r){
        float v = acc[m][n][r];
        if constexpr (std::is_same<OutT, unsigned short>::value) C[base + (size_t)r*N] = f2bf(v);
        else                                                     C[base + (size_t)r*N] = v;
      }
    }
}

// ---- causal GQA attention with tanh soft-cap, QBLK=64, KVBLK=64 ----
// Soft-cap bounds scores to [-30,30] -> fixed-max softmax: p = exp(s-30), no online max.
__global__ void attn_k(const unsigned short* __restrict__ Q,
                       const unsigned short* __restrict__ Kp,
                       const unsigned short* __restrict__ Vp,
                       unsigned short* __restrict__ ctx){
  __shared__ __align__(16) unsigned short Ks[64*128];   // [kv][d], XOR-swz (kv&7)<<4
  __shared__ __align__(16) unsigned short Vt[128*64];   // [d][kv], XOR-swz ((d^(d>>3))&7)<<4
  __shared__ __align__(16) unsigned short Ps[4*16*64];  // per-wave [16][64], XOR-swz (row&7)<<4
  const int qt = blockIdx.x, h = blockIdx.y, b = blockIdx.z;
  const int kvh = h >> 2;
  const int tid = threadIdx.x, w = tid >> 6, lane = tid & 63;
  const int q0 = qt * 64;
  const int lrow = lane & 15, lhi = lane >> 4;

  // Q fragments (direct from global, 16 rows per wave)
  bf16x8 qf[4];
  {
    const unsigned short* qb = Q + (size_t)(b*SS + q0 + w*16 + lrow) * 4096 + h*HD + lhi*8;
    #pragma unroll
    for (int ks = 0; ks < 4; ++ks) qf[ks] = *(const bf16x8*)(qb + ks*32);
  }

  f32x4 o[8] = {};
  float lsum[4] = {0.f, 0.f, 0.f, 0.f};

  const unsigned short* Kbase = Kp + (size_t)b * SS * 1024 + kvh * HD;
  const unsigned short* Vbase = Vp + (size_t)b * SS * 1024 + kvh * HD;
  const int skv = tid >> 4;        // 0..15
  const int sd  = (tid & 15) * 8;  // 0..120

  for (int t = 0; t <= qt; ++t){
    __syncthreads();
    // stage K tile [64][128] and V^T tile [128][64]
    #pragma unroll
    for (int c = 0; c < 4; ++c){
      int kv = c*16 + skv;
      bf16x8 k8 = *(const bf16x8*)(Kbase + (size_t)(t*64 + kv) * 1024 + sd);
      int kbyte = (kv*256 + sd*2) ^ ((kv & 7) << 4);
      *(bf16x8*)((char*)Ks + kbyte) = k8;
      bf16x8 v8 = *(const bf16x8*)(Vbase + (size_t)(t*64 + kv) * 1024 + sd);
      #pragma unroll
      for (int j = 0; j < 8; ++j){
        int d = sd + j;
        int vbyte = (d*128 + kv*2) ^ (((d ^ (d >> 3)) & 7) << 4);
        *(unsigned short*)((char*)Vt + vbyte) = (unsigned short)v8[j];
      }
    }
    __syncthreads();

    // S = Q K^T  (per wave: 16 q-rows x 64 kv-cols)
    f32x4 sacc[4];
    #pragma unroll
    for (int cf = 0; cf < 4; ++cf){
      f32x4 a = {0.f, 0.f, 0.f, 0.f};
      int row = cf*16 + lrow;
      #pragma unroll
      for (int ks = 0; ks < 4; ++ks){
        int kbyte = (row*256 + (ks*32 + lhi*8)*2) ^ ((row & 7) << 4);
        bf16x8 kf = *(const bf16x8*)((char*)Ks + kbyte);
        a = __builtin_amdgcn_mfma_f32_16x16x32_bf16(qf[ks], kf, a, 0, 0, 0);
      }
      sacc[cf] = a;
    }

    // soft-cap + causal mask + exp(s-30); write P (bf16) to wave-private LDS
    unsigned short* Pw = Ps + w * (16*64);
    float psum[4] = {0.f, 0.f, 0.f, 0.f};
    #pragma unroll
    for (int cf = 0; cf < 4; ++cf){
      int kvg = t*64 + cf*16 + lrow;
      #pragma unroll
      for (int r = 0; r < 4; ++r){
        float sc = sacc[cf][r] * ATTN_MULT;
        sc = 30.f * tanhf(sc * (1.f/30.f));
        int qg = q0 + w*16 + lhi*4 + r;
        float p = (kvg <= qg) ? __expf(sc - 30.f) : 0.f;
        unsigned short pb = f2bf(p);
        psum[r] += bf2f(pb);   // sum the value we'll actually multiply
        int prow = lhi*4 + r;
        int pbyte = (prow*128 + (cf*16 + lrow)*2) ^ ((prow & 7) << 4);
        *(unsigned short*)((char*)Pw + pbyte) = pb;
      }
    }
    #pragma unroll
    for (int r = 0; r < 4; ++r){
      float s = psum[r];
      s += __shfl_xor(s, 1);
      s += __shfl_xor(s, 2);
      s += __shfl_xor(s, 4);
      s += __shfl_xor(s, 8);
      lsum[r] += s;
    }

    // O += P V
    bf16x8 pf[2];
    #pragma unroll
    for (int ks = 0; ks < 2; ++ks){
      int pbyte = (lrow*128 + (ks*32 + lhi*8)*2) ^ ((lrow & 7) << 4);
      pf[ks] = *(const bf16x8*)((char*)Pw + pbyte);
    }
    #pragma unroll
    for (int df = 0; df < 8; ++df){
      f32x4 a = o[df];
      #pragma unroll
      for (int ks = 0; ks < 2; ++ks){
        int d = df*16 + lrow;
        int vbyte = (d*128 + (ks*32 + lhi*8)*2) ^ (((d ^ (d >> 3)) & 7) << 4);
        bf16x8 vf = *(const bf16x8*)((char*)Vt + vbyte);
        a = __builtin_amdgcn_mfma_f32_16x16x32_bf16(pf[ks], vf, a, 0, 0, 0);
      }
      o[df] = a;
    }
  }

  // normalize and store context (bf16)
  #pragma unroll
  for (int r = 0; r < 4; ++r){
    float inv = 1.f / lsum[r];
    size_t base = (size_t)(b*SS + q0 + w*16 + lhi*4 + r) * 4096 + h*HD + lrow;
    #pragma unroll
    for (int df = 0; df < 8; ++df)
      ctx[base + df*16] = f2bf(o[df][r] * inv);
  }
}

// ---- workspace layout (bytes) ----
#define O_HSB   ((size_t)0)            // 33,554,432  hs bf16 [4096][4096]
#define O_WQT   ((size_t)33554432)     // 33,554,432  WqT bf16 [4096][4096]
#define O_WKT   ((size_t)67108864)     //  8,388,608  WkT bf16 [1024][4096]
#define O_WVT   ((size_t)75497472)     //  8,388,608  WvT bf16 [1024][4096]
#define O_WOT   ((size_t)83886080)     // 33,554,432  WoT bf16 [4096][4096]
#define O_Q     ((size_t)117440512)    // 33,554,432  Q bf16 [4096][4096]
#define O_K     ((size_t)150994944)    //  8,388,608  K bf16 [4096][1024]
#define O_V     ((size_t)159383552)    //  8,388,608  V bf16 [4096][1024]
#define O_CTX   ((size_t)167772160)    // 33,554,432  ctx bf16 [4096][4096]
#define WS_NEED ((size_t)201326592)

extern "C" void kernel_launch(void* const* d_in, const int* in_sizes, int n_in,
                              void* d_out, int out_size, void* d_ws, size_t ws_size,
                              hipStream_t stream){
  if (ws_size < WS_NEED) return;
  const float* hs = (const float*)d_in[0];
  const float* Wq = (const float*)d_in[1];
  const float* Wk = (const float*)d_in[2];
  const float* Wv = (const float*)d_in[3];
  const float* Wo = (const float*)d_in[4];
  char* ws = (char*)d_ws;
  unsigned short* hsb = (unsigned short*)(ws + O_HSB);
  unsigned short* WqT = (unsigned short*)(ws + O_WQT);
  unsigned short* WkT = (unsigned short*)(ws + O_WKT);
  unsigned short* WvT = (unsigned short*)(ws + O_WVT);
  unsigned short* WoT = (unsigned short*)(ws + O_WOT);
  unsigned short* Qb  = (unsigned short*)(ws + O_Q);
  unsigned short* Kb  = (unsigned short*)(ws + O_K);
  unsigned short* Vb  = (unsigned short*)(ws + O_V);
  unsigned short* ctxb= (unsigned short*)(ws + O_CTX);

  // hs -> bf16
  cvt_f32_bf16_k<<<dim3((NTOK*HIDDEN/8)/256), dim3(256), 0, stream>>>(hs, hsb, NTOK*HIDDEN/8);
  // weights -> transposed bf16 ([N][K])
  transpose_cvt_k<<<dim3(128,128), dim3(32,8), 0, stream>>>(Wq, WqT, 4096, 4096);
  transpose_cvt_k<<<dim3(32,128),  dim3(32,8), 0, stream>>>(Wk, WkT, 4096, 1024);
  transpose_cvt_k<<<dim3(32,128),  dim3(32,8), 0, stream>>>(Wv, WvT, 4096, 1024);
  transpose_cvt_k<<<dim3(128,128), dim3(32,8), 0, stream>>>(Wo, WoT, 4096, 4096);
  // projections
  gemm_bt_k<unsigned short><<<dim3(32,32), dim3(256), 0, stream>>>(hsb, WqT, Qb, 4096, 4096, 4096);
  gemm_bt_k<unsigned short><<<dim3(8,32),  dim3(256), 0, stream>>>(hsb, WkT, Kb, 4096, 1024, 4096);
  gemm_bt_k<unsigned short><<<dim3(8,32),  dim3(256), 0, stream>>>(hsb, WvT, Vb, 4096, 1024, 4096);
  // attention
  attn_k<<<dim3(SS/64, NHEADS, BB), dim3(256), 0, stream>>>(Qb, Kb, Vb, ctxb);
  // output projection (fp32 out)
  gemm_bt_k<float><<<dim3(32,32), dim3(256), 0, stream>>>(ctxb, WoT, (float*)d_out, 4096, 4096, 4096);
}

// Round 2
// 1027.171 us; speedup vs baseline: 1.3265x; 1.3265x over previous
//
#include <hip/hip_runtime.h>
#include <hip/hip_bf16.h>
#include <type_traits>
#include <cmath>

// ---- problem constants ----
#define HIDDEN 4096
#define NHEADS 32
#define NKV 8
#define HD 128
#define BB 2
#define SS 2048
#define NTOK (BB*SS)                  // 4096 tokens
#define ATTN_MULT 0.08838834764831845f

using bf16x8 = __attribute__((ext_vector_type(8))) short;
using f32x4  = __attribute__((ext_vector_type(4))) float;

using gas = __attribute__((address_space(1))) const void;
using las = __attribute__((address_space(3))) void;

__device__ __forceinline__ unsigned short f2bf(float f){
  unsigned int u = __builtin_bit_cast(unsigned int, f);
  u += 0x7fffu + ((u >> 16) & 1u);
  return (unsigned short)(u >> 16);
}
__device__ __forceinline__ float bf2f(unsigned short b){
  unsigned int u = ((unsigned int)b) << 16;
  return __builtin_bit_cast(float, u);
}

// ---- fp32 -> bf16 elementwise (8 el/thread) ----
__global__ void cvt_f32_bf16_k(const float* __restrict__ in, unsigned short* __restrict__ out, int n8){
  int i = blockIdx.x * blockDim.x + threadIdx.x;
  if (i >= n8) return;
  const float4* p = (const float4*)in + (size_t)i * 2;
  float4 a = p[0], b = p[1];
  bf16x8 o;
  o[0]=f2bf(a.x); o[1]=f2bf(a.y); o[2]=f2bf(a.z); o[3]=f2bf(a.w);
  o[4]=f2bf(b.x); o[5]=f2bf(b.y); o[6]=f2bf(b.z); o[7]=f2bf(b.w);
  ((bf16x8*)out)[i] = o;
}

// ---- W[K][N] fp32 -> WT[N][K] bf16 (tiled transpose) ----
__global__ void transpose_cvt_k(const float* __restrict__ W, unsigned short* __restrict__ WT, int K, int N){
  __shared__ float tile[32][33];
  int n0 = blockIdx.x * 32, k0 = blockIdx.y * 32;
  int tx = threadIdx.x, ty = threadIdx.y; // 32 x 8
  #pragma unroll
  for (int i = 0; i < 4; ++i)
    tile[ty*4+i][tx] = W[(size_t)(k0 + ty*4 + i) * N + n0 + tx];
  __syncthreads();
  #pragma unroll
  for (int i = 0; i < 4; ++i)
    WT[(size_t)(n0 + ty*4 + i) * K + k0 + tx] = f2bf(tile[tx][ty*4+i]);
}

// ---- bf16 V[4096][1024] -> VT[(b*1024+c)][s] (tiled transpose, batch remap) ----
__global__ void transpose_v_k(const unsigned short* __restrict__ in, unsigned short* __restrict__ out){
  __shared__ unsigned short tile[32][33];
  const int C = 1024;
  int c0 = blockIdx.x * 32, r0 = blockIdx.y * 32;
  int tx = threadIdx.x, ty = threadIdx.y; // 32 x 8
  #pragma unroll
  for (int i = 0; i < 4; ++i)
    tile[ty*4+i][tx] = in[(size_t)(r0 + ty*4 + i) * C + c0 + tx];
  __syncthreads();
  #pragma unroll
  for (int i = 0; i < 4; ++i){
    int c = c0 + ty*4 + i, r = r0 + tx;
    out[((size_t)((r >> 11) * C + c)) * 2048 + (r & 2047)] = tile[tx][ty*4+i];
  }
}

// ---- bf16 GEMM: C[M][N] = A[M][K] * BT[N][K]^T, m97-style 128x128x32 ----
template<typename OutT>
__global__ void gemm_bt_k(const unsigned short* __restrict__ A,
                          const unsigned short* __restrict__ BT,
                          OutT* __restrict__ C, int M, int N, int K){
  __shared__ __align__(16) unsigned short As[128*32];
  __shared__ __align__(16) unsigned short Bs[128*32];
  const int m0 = blockIdx.y * 128, n0 = blockIdx.x * 128;
  const int tid = threadIdx.x, w = tid >> 6, lane = tid & 63;
  const int wr = w >> 1, wc = w & 1;
  const int lrow = lane & 15, lk = (lane >> 4) * 8;
  const int arow = lane >> 2, acol = (lane & 3) * 8;   // staging: lane covers 8 el

  f32x4 acc[4][4] = {};

  for (int k0 = 0; k0 < K; k0 += 32){
    #pragma unroll
    for (int i = 0; i < 2; ++i){
      int chunk = w*2 + i;  // 0..7, each 512 el (16 rows x 32 k)
      const unsigned short* ga = A  + (size_t)(m0 + chunk*16 + arow) * K + k0 + acol;
      const unsigned short* gb = BT + (size_t)(n0 + chunk*16 + arow) * K + k0 + acol;
      __builtin_amdgcn_global_load_lds((gas*)ga, (las*)(As + chunk*512), 16, 0, 0);
      __builtin_amdgcn_global_load_lds((gas*)gb, (las*)(Bs + chunk*512), 16, 0, 0);
    }
    __syncthreads();
    bf16x8 af[4], bfr[4];
    #pragma unroll
    for (int m = 0; m < 4; ++m) af[m]  = *(const bf16x8*)&As[(wr*64 + m*16 + lrow)*32 + lk];
    #pragma unroll
    for (int n = 0; n < 4; ++n) bfr[n] = *(const bf16x8*)&Bs[(wc*64 + n*16 + lrow)*32 + lk];
    #pragma unroll
    for (int m = 0; m < 4; ++m)
      #pragma unroll
      for (int n = 0; n < 4; ++n)
        acc[m][n] = __builtin_amdgcn_mfma_f32_16x16x32_bf16(af[m], bfr[n], acc[m][n], 0, 0, 0);
    __syncthreads();
  }

  const int crow = (lane >> 4) * 4, ccol = lane & 15;
  #pragma unroll
  for (int m = 0; m < 4; ++m)
    #pragma unroll
    for (int n = 0; n < 4; ++n){
      size_t base = (size_t)(m0 + wr*64 + m*16 + crow) * N + n0 + wc*64 + n*16 + ccol;
      #pragma unroll
      for (int r = 0; r < 4; ++r){
        float v = acc[m][n][r];
        if constexpr (std::is_same<OutT, unsigned short>::value) C[base + (size_t)r*N] = f2bf(v);
        else                                                     C[base + (size_t)r*N] = v;
      }
    }
}

// ---- causal GQA attention with tanh soft-cap, QBLK=64, KVBLK=64 ----
// p = exp(30*tanh(s/30) - 30) = exp(-60/(exp(s/15)+1))  -> 2 exp + 1 rcp, no libm.
// K tile [64][128] and V^T tile [128][64] staged via global_load_lds with
// pre-swizzled SOURCE addresses (LDS dest stays linear, reads use the XOR).
__global__ __launch_bounds__(256, 4)
void attn_k(const unsigned short* __restrict__ Q,
            const unsigned short* __restrict__ Kp,
            const unsigned short* __restrict__ VTp,
            unsigned short* __restrict__ ctx){
  __shared__ __align__(16) unsigned short Ks[64*128];   // [kv][d], read-XOR (kv&7)<<4
  __shared__ __align__(16) unsigned short Vt[128*64];   // [d][kv], read-XOR ((d^(d>>3))&7)<<4
  __shared__ __align__(16) unsigned short Ps[4*16*64];  // per-wave [16][64], XOR ((r^(r>>3))&7)<<4
  const int qt = (SS/64 - 1) - blockIdx.x;  // heaviest blocks first
  const int h = blockIdx.y, b = blockIdx.z;
  const int kvh = h >> 2;
  const int tid = threadIdx.x, w = tid >> 6, lane = tid & 63;
  const int q0 = qt * 64;
  const int lrow = lane & 15, lhi = lane >> 4;

  // Q fragments (direct from global, 16 rows per wave)
  bf16x8 qf[4];
  {
    const unsigned short* qb = Q + (size_t)(b*SS + q0 + w*16 + lrow) * 4096 + h*HD + lhi*8;
    #pragma unroll
    for (int ks = 0; ks < 4; ++ks) qf[ks] = *(const bf16x8*)(qb + ks*32);
  }

  f32x4 o[8] = {};
  float lsum[4] = {0.f, 0.f, 0.f, 0.f};

  const unsigned short* Kbh  = Kp  + (size_t)b * SS * 1024 + kvh * HD;
  const unsigned short* VTbh = VTp + ((size_t)b * 1024 + kvh * HD) * SS;

  for (int t = 0; t <= qt; ++t){
    __syncthreads();
    // stage K tile (1024 x 16B chunks) and V^T tile (1024 chunks) via global_load_lds
    #pragma unroll
    for (int it = 0; it < 4; ++it){
      int cbase = (it*4 + w) * 64;       // wave-uniform
      int chunk = cbase + lane;          // per-lane
      int kkv = chunk >> 4, kc = chunk & 15;
      const unsigned short* gk = Kbh + (size_t)(t*64 + kkv) * 1024 + ((kc ^ (kkv & 7)) << 3);
      __builtin_amdgcn_global_load_lds((gas*)gk, (las*)(Ks + cbase*8), 16, 0, 0);
      int vd = chunk >> 3, vc = chunk & 7;
      const unsigned short* gv = VTbh + (size_t)vd * SS + t*64 + ((vc ^ ((vd ^ (vd >> 3)) & 7)) << 3);
      __builtin_amdgcn_global_load_lds((gas*)gv, (las*)(Vt + cbase*8), 16, 0, 0);
    }
    __syncthreads();

    // S = Q K^T  (per wave: 16 q-rows x 64 kv-cols)
    f32x4 sacc[4];
    #pragma unroll
    for (int cf = 0; cf < 4; ++cf){
      f32x4 a = {0.f, 0.f, 0.f, 0.f};
      int row = cf*16 + lrow;
      #pragma unroll
      for (int ks = 0; ks < 4; ++ks){
        int kbyte = (row*256 + (ks*32 + lhi*8)*2) ^ ((row & 7) << 4);
        bf16x8 kf = *(const bf16x8*)((char*)Ks + kbyte);
        a = __builtin_amdgcn_mfma_f32_16x16x32_bf16(qf[ks], kf, a, 0, 0, 0);
      }
      sacc[cf] = a;
    }

    // soft-cap + causal mask + exp(s-30); write P (bf16) to wave-private LDS
    unsigned short* Pw = Ps + w * (16*64);
    float psum[4] = {0.f, 0.f, 0.f, 0.f};
    #pragma unroll
    for (int cf = 0; cf < 4; ++cf){
      int kvg = t*64 + cf*16 + lrow;
      #pragma unroll
      for (int r = 0; r < 4; ++r){
        float sc = sacc[cf][r] * ATTN_MULT;
        float e  = __expf(sc * (2.f/30.f));                       // exp(s/15)
        float ex = -60.f * __builtin_amdgcn_rcpf(e + 1.f);        // 30*tanh(s/30)-30
        int qg = q0 + w*16 + lhi*4 + r;
        float p = (kvg <= qg) ? __expf(ex) : 0.f;
        psum[r] += p;
        int prow = lhi*4 + r;
        int pbyte = (prow*128 + (cf*16 + lrow)*2) ^ (((prow ^ (prow >> 3)) & 7) << 4);
        *(unsigned short*)((char*)Pw + pbyte) = f2bf(p);
      }
    }
    #pragma unroll
    for (int r = 0; r < 4; ++r){
      float s = psum[r];
      s += __shfl_xor(s, 1);
      s += __shfl_xor(s, 2);
      s += __shfl_xor(s, 4);
      s += __shfl_xor(s, 8);
      lsum[r] += s;
    }

    // O += P V
    bf16x8 pf[2];
    #pragma unroll
    for (int ks = 0; ks < 2; ++ks){
      int pbyte = (lrow*128 + (ks*32 + lhi*8)*2) ^ (((lrow ^ (lrow >> 3)) & 7) << 4);
      pf[ks] = *(const bf16x8*)((char*)Pw + pbyte);
    }
    #pragma unroll
    for (int df = 0; df < 8; ++df){
      f32x4 a = o[df];
      #pragma unroll
      for (int ks = 0; ks < 2; ++ks){
        int d = df*16 + lrow;
        int vbyte = (d*128 + (ks*32 + lhi*8)*2) ^ (((d ^ (d >> 3)) & 7) << 4);
        bf16x8 vf = *(const bf16x8*)((char*)Vt + vbyte);
        a = __builtin_amdgcn_mfma_f32_16x16x32_bf16(pf[ks], vf, a, 0, 0, 0);
      }
      o[df] = a;
    }
  }

  // normalize and store context (bf16)
  #pragma unroll
  for (int r = 0; r < 4; ++r){
    float inv = 1.f / lsum[r];
    size_t base = (size_t)(b*SS + q0 + w*16 + lhi*4 + r) * 4096 + h*HD + lrow;
    #pragma unroll
    for (int df = 0; df < 8; ++df)
      ctx[base + df*16] = f2bf(o[df][r] * inv);
  }
}

// ---- workspace layout (bytes) ----
#define O_HSB   ((size_t)0)            // 33,554,432  hs bf16 [4096][4096]
#define O_WQT   ((size_t)33554432)     // 33,554,432  WqT bf16 [4096][4096]; later reused for VT (8MB)
#define O_WKT   ((size_t)67108864)     //  8,388,608  WkT bf16 [1024][4096]
#define O_WVT   ((size_t)75497472)     //  8,388,608  WvT bf16 [1024][4096]
#define O_WOT   ((size_t)83886080)     // 33,554,432  WoT bf16 [4096][4096]
#define O_Q     ((size_t)117440512)    // 33,554,432  Q bf16 [4096][4096]
#define O_K     ((size_t)150994944)    //  8,388,608  K bf16 [4096][1024]
#define O_V     ((size_t)159383552)    //  8,388,608  V bf16 [4096][1024]
#define O_CTX   ((size_t)167772160)    // 33,554,432  ctx bf16 [4096][4096]
#define WS_NEED ((size_t)201326592)

extern "C" void kernel_launch(void* const* d_in, const int* in_sizes, int n_in,
                              void* d_out, int out_size, void* d_ws, size_t ws_size,
                              hipStream_t stream){
  if (ws_size < WS_NEED) return;
  const float* hs = (const float*)d_in[0];
  const float* Wq = (const float*)d_in[1];
  const float* Wk = (const float*)d_in[2];
  const float* Wv = (const float*)d_in[3];
  const float* Wo = (const float*)d_in[4];
  char* ws = (char*)d_ws;
  unsigned short* hsb = (unsigned short*)(ws + O_HSB);
  unsigned short* WqT = (unsigned short*)(ws + O_WQT);
  unsigned short* WkT = (unsigned short*)(ws + O_WKT);
  unsigned short* WvT = (unsigned short*)(ws + O_WVT);
  unsigned short* WoT = (unsigned short*)(ws + O_WOT);
  unsigned short* Qb  = (unsigned short*)(ws + O_Q);
  unsigned short* Kb  = (unsigned short*)(ws + O_K);
  unsigned short* Vb  = (unsigned short*)(ws + O_V);
  unsigned short* ctxb= (unsigned short*)(ws + O_CTX);
  unsigned short* VTb = (unsigned short*)(ws + O_WQT);  // reuse WqT region after Q proj

  // hs -> bf16
  cvt_f32_bf16_k<<<dim3((NTOK*HIDDEN/8)/256), dim3(256), 0, stream>>>(hs, hsb, NTOK*HIDDEN/8);
  // weights -> transposed bf16 ([N][K])
  transpose_cvt_k<<<dim3(128,128), dim3(32,8), 0, stream>>>(Wq, WqT, 4096, 4096);
  transpose_cvt_k<<<dim3(32,128),  dim3(32,8), 0, stream>>>(Wk, WkT, 4096, 1024);
  transpose_cvt_k<<<dim3(32,128),  dim3(32,8), 0, stream>>>(Wv, WvT, 4096, 1024);
  transpose_cvt_k<<<dim3(128,128), dim3(32,8), 0, stream>>>(Wo, WoT, 4096, 4096);
  // projections (Q first: its weight buffer is recycled for VT)
  gemm_bt_k<unsigned short><<<dim3(32,32), dim3(256), 0, stream>>>(hsb, WqT, Qb, 4096, 4096, 4096);
  gemm_bt_k<unsigned short><<<dim3(8,32),  dim3(256), 0, stream>>>(hsb, WkT, Kb, 4096, 1024, 4096);
  gemm_bt_k<unsigned short><<<dim3(8,32),  dim3(256), 0, stream>>>(hsb, WvT, Vb, 4096, 1024, 4096);
  // V -> V^T ([b*1024+c][s])
  transpose_v_k<<<dim3(32,128), dim3(32,8), 0, stream>>>(Vb, VTb);
  // attention
  attn_k<<<dim3(SS/64, NHEADS, BB), dim3(256), 0, stream>>>(Qb, Kb, VTb, ctxb);
  // output projection (fp32 out)
  gemm_bt_k<float><<<dim3(32,32), dim3(256), 0, stream>>>(ctxb, WoT, (float*)d_out, 4096, 4096, 4096);
}

// Round 3
// 819.460 us; speedup vs baseline: 1.6627x; 1.2535x over previous
//
#include <hip/hip_runtime.h>
#include <hip/hip_bf16.h>
#include <type_traits>
#include <cmath>

// ---- problem constants ----
#define HIDDEN 4096
#define NHEADS 32
#define NKV 8
#define HD 128
#define BB 2
#define SS 2048
#define NTOK (BB*SS)                  // 4096 tokens
#define ATTN_MULT 0.08838834764831845f

using bf16x8 = __attribute__((ext_vector_type(8))) short;
using f32x4  = __attribute__((ext_vector_type(4))) float;

using gas = __attribute__((address_space(1))) const void;
using las = __attribute__((address_space(3))) void;

__device__ __forceinline__ unsigned short f2bf(float f){
  unsigned int u = __builtin_bit_cast(unsigned int, f);
  u += 0x7fffu + ((u >> 16) & 1u);
  return (unsigned short)(u >> 16);
}
__device__ __forceinline__ float bf2f(unsigned short b){
  unsigned int u = ((unsigned int)b) << 16;
  return __builtin_bit_cast(float, u);
}

// ---- fp32 -> bf16 elementwise (8 el/thread) ----
__global__ void cvt_f32_bf16_k(const float* __restrict__ in, unsigned short* __restrict__ out, int n8){
  int i = blockIdx.x * blockDim.x + threadIdx.x;
  if (i >= n8) return;
  const float4* p = (const float4*)in + (size_t)i * 2;
  float4 a = p[0], b = p[1];
  bf16x8 o;
  o[0]=f2bf(a.x); o[1]=f2bf(a.y); o[2]=f2bf(a.z); o[3]=f2bf(a.w);
  o[4]=f2bf(b.x); o[5]=f2bf(b.y); o[6]=f2bf(b.z); o[7]=f2bf(b.w);
  ((bf16x8*)out)[i] = o;
}

// ---- W[K][N] fp32 -> WT[N][K] bf16 (tiled transpose) ----
__global__ void transpose_cvt_k(const float* __restrict__ W, unsigned short* __restrict__ WT, int K, int N){
  __shared__ float tile[32][33];
  int n0 = blockIdx.x * 32, k0 = blockIdx.y * 32;
  int tx = threadIdx.x, ty = threadIdx.y; // 32 x 8
  #pragma unroll
  for (int i = 0; i < 4; ++i)
    tile[ty*4+i][tx] = W[(size_t)(k0 + ty*4 + i) * N + n0 + tx];
  __syncthreads();
  #pragma unroll
  for (int i = 0; i < 4; ++i)
    WT[(size_t)(n0 + ty*4 + i) * K + k0 + tx] = f2bf(tile[tx][ty*4+i]);
}

// ---- bf16 V[4096][1024] -> VT[(b*1024+c)][s] (tiled transpose, batch remap) ----
__global__ void transpose_v_k(const unsigned short* __restrict__ in, unsigned short* __restrict__ out){
  __shared__ unsigned short tile[32][33];
  const int C = 1024;
  int c0 = blockIdx.x * 32, r0 = blockIdx.y * 32;
  int tx = threadIdx.x, ty = threadIdx.y; // 32 x 8
  #pragma unroll
  for (int i = 0; i < 4; ++i)
    tile[ty*4+i][tx] = in[(size_t)(r0 + ty*4 + i) * C + c0 + tx];
  __syncthreads();
  #pragma unroll
  for (int i = 0; i < 4; ++i){
    int c = c0 + ty*4 + i, r = r0 + tx;
    out[((size_t)((r >> 11) * C + c)) * 2048 + (r & 2047)] = tile[tx][ty*4+i];
  }
}

// ---- bf16 GEMM: C[M][N] = A[M][K] * BT[N][K]^T, m97-style 128x128x32 ----
template<typename OutT>
__global__ void gemm_bt_k(const unsigned short* __restrict__ A,
                          const unsigned short* __restrict__ BT,
                          OutT* __restrict__ C, int M, int N, int K){
  __shared__ __align__(16) unsigned short As[128*32];
  __shared__ __align__(16) unsigned short Bs[128*32];
  const int m0 = blockIdx.y * 128, n0 = blockIdx.x * 128;
  const int tid = threadIdx.x, w = tid >> 6, lane = tid & 63;
  const int wr = w >> 1, wc = w & 1;
  const int lrow = lane & 15, lk = (lane >> 4) * 8;
  const int arow = lane >> 2, acol = (lane & 3) * 8;   // staging: lane covers 8 el

  f32x4 acc[4][4] = {};

  for (int k0 = 0; k0 < K; k0 += 32){
    #pragma unroll
    for (int i = 0; i < 2; ++i){
      int chunk = w*2 + i;  // 0..7, each 512 el (16 rows x 32 k)
      const unsigned short* ga = A  + (size_t)(m0 + chunk*16 + arow) * K + k0 + acol;
      const unsigned short* gb = BT + (size_t)(n0 + chunk*16 + arow) * K + k0 + acol;
      __builtin_amdgcn_global_load_lds((gas*)ga, (las*)(As + chunk*512), 16, 0, 0);
      __builtin_amdgcn_global_load_lds((gas*)gb, (las*)(Bs + chunk*512), 16, 0, 0);
    }
    __syncthreads();
    bf16x8 af[4], bfr[4];
    #pragma unroll
    for (int m = 0; m < 4; ++m) af[m]  = *(const bf16x8*)&As[(wr*64 + m*16 + lrow)*32 + lk];
    #pragma unroll
    for (int n = 0; n < 4; ++n) bfr[n] = *(const bf16x8*)&Bs[(wc*64 + n*16 + lrow)*32 + lk];
    #pragma unroll
    for (int m = 0; m < 4; ++m)
      #pragma unroll
      for (int n = 0; n < 4; ++n)
        acc[m][n] = __builtin_amdgcn_mfma_f32_16x16x32_bf16(af[m], bfr[n], acc[m][n], 0, 0, 0);
    __syncthreads();
  }

  const int crow = (lane >> 4) * 4, ccol = lane & 15;
  #pragma unroll
  for (int m = 0; m < 4; ++m)
    #pragma unroll
    for (int n = 0; n < 4; ++n){
      size_t base = (size_t)(m0 + wr*64 + m*16 + crow) * N + n0 + wc*64 + n*16 + ccol;
      #pragma unroll
      for (int r = 0; r < 4; ++r){
        float v = acc[m][n][r];
        if constexpr (std::is_same<OutT, unsigned short>::value) C[base + (size_t)r*N] = f2bf(v);
        else                                                     C[base + (size_t)r*N] = v;
      }
    }
}

// ---- causal GQA attention, QBLK=128 (8 waves), KVBLK=64, double-buffered ----
// p = exp(30*tanh(s/30) - 30) = exp(-60/(exp(s/15)+1))  -> 2 exp + 1 rcp.
// 2-phase pipeline: issue next tile's global_load_lds, compute current, one
// barrier per tile. XCD-chunked block swizzle keeps each (b,kvh) K/V stream
// (1 MB) resident in one XCD's L2.
__global__ __launch_bounds__(512, 4)
void attn_k(const unsigned short* __restrict__ Q,
            const unsigned short* __restrict__ Kp,
            const unsigned short* __restrict__ VTp,
            unsigned short* __restrict__ ctx){
  __shared__ __align__(16) unsigned short Ks[2][64*128];   // [kv][d], read-XOR (kv&7)<<4
  __shared__ __align__(16) unsigned short Vt[2][128*64];   // [d][kv], read-XOR ((d^(d>>3))&7)<<4
  __shared__ __align__(16) unsigned short Ps[8][16*64];    // per-wave, XOR ((r^(r>>3))&7)<<4

  // XCD-chunked decode: xcd = wg&7 hosts 2 (b,kvh) groups; heavy qt first.
  const int Wb = blockIdx.x;
  const int xcd = Wb & 7, slot = Wb >> 3;
  const int group = xcd*2 + (slot >> 6);     // 0..15 = b*8 + kvh
  const int within = slot & 63;              // 0..63 = (h&3)*16 + (15-qt)
  const int b = group >> 3, kvh = group & 7;
  const int h = (kvh << 2) + (within >> 4);
  const int qt = 15 - (within & 15);

  const int tid = threadIdx.x, w = tid >> 6, lane = tid & 63;
  const int q0 = qt * 128;
  const int nt = 2*qt + 2;
  const int lrow = lane & 15, lhi = lane >> 4;

  // Q fragments (wave w owns q rows q0+w*16 .. +15)
  bf16x8 qf[4];
  {
    const unsigned short* qb = Q + (size_t)(b*SS + q0 + w*16 + lrow) * 4096 + h*HD + lhi*8;
    #pragma unroll
    for (int ks = 0; ks < 4; ++ks) qf[ks] = *(const bf16x8*)(qb + ks*32);
  }

  f32x4 o[8] = {};
  float lsum[4] = {0.f, 0.f, 0.f, 0.f};

  const unsigned short* Kbh  = Kp  + (size_t)b * SS * 1024 + kvh * HD;
  const unsigned short* VTbh = VTp + ((size_t)b * 1024 + kvh * HD) * SS;

  auto STAGE = [&](int db, int t){
    #pragma unroll
    for (int it = 0; it < 2; ++it){
      int cbase = it*512 + w*64;       // wave-uniform
      int c = cbase + lane;            // chunk 0..1023 (16B each)
      int kkv = c >> 4, kc = c & 15;
      const unsigned short* gk = Kbh + (size_t)(t*64 + kkv) * 1024 + ((kc ^ (kkv & 7)) << 3);
      __builtin_amdgcn_global_load_lds((gas*)gk, (las*)(&Ks[db][0] + cbase*8), 16, 0, 0);
      int vd = c >> 3, vc = c & 7;
      const unsigned short* gv = VTbh + (size_t)vd * SS + t*64 + ((vc ^ ((vd ^ (vd >> 3)) & 7)) << 3);
      __builtin_amdgcn_global_load_lds((gas*)gv, (las*)(&Vt[db][0] + cbase*8), 16, 0, 0);
    }
  };

  STAGE(0, 0);
  __syncthreads();

  for (int t = 0; t < nt; ++t){
    const int db = t & 1;
    if (t + 1 < nt) STAGE(db ^ 1, t + 1);

    // skip waves whose entire q-range is above-diagonal for this kv tile
    if (t*64 <= q0 + w*16 + 15){
      const char* Kc = (const char*)&Ks[db][0];
      const char* Vc = (const char*)&Vt[db][0];

      // S = Q K^T  (16 q-rows x 64 kv-cols per wave)
      f32x4 sacc[4];
      #pragma unroll
      for (int cf = 0; cf < 4; ++cf){
        f32x4 a = {0.f, 0.f, 0.f, 0.f};
        int row = cf*16 + lrow;
        #pragma unroll
        for (int ks = 0; ks < 4; ++ks){
          int kbyte = (row*256 + (ks*32 + lhi*8)*2) ^ ((row & 7) << 4);
          bf16x8 kf = *(const bf16x8*)(Kc + kbyte);
          a = __builtin_amdgcn_mfma_f32_16x16x32_bf16(qf[ks], kf, a, 0, 0, 0);
        }
        sacc[cf] = a;
      }

      // soft-cap + causal mask + exp(s-30); P -> wave-private LDS
      unsigned short* Pw = &Ps[w][0];
      float psum[4] = {0.f, 0.f, 0.f, 0.f};
      #pragma unroll
      for (int cf = 0; cf < 4; ++cf){
        int kvg = t*64 + cf*16 + lrow;
        #pragma unroll
        for (int r = 0; r < 4; ++r){
          float sc = sacc[cf][r] * ATTN_MULT;
          float e  = __expf(sc * (2.f/30.f));
          float ex = -60.f * __builtin_amdgcn_rcpf(e + 1.f);
          int qg = q0 + w*16 + lhi*4 + r;
          float p = (kvg <= qg) ? __expf(ex) : 0.f;
          psum[r] += p;
          int prow = lhi*4 + r;
          int pbyte = (prow*128 + (cf*16 + lrow)*2) ^ (((prow ^ (prow >> 3)) & 7) << 4);
          *(unsigned short*)((char*)Pw + pbyte) = f2bf(p);
        }
      }
      #pragma unroll
      for (int r = 0; r < 4; ++r){
        float s = psum[r];
        s += __shfl_xor(s, 1);
        s += __shfl_xor(s, 2);
        s += __shfl_xor(s, 4);
        s += __shfl_xor(s, 8);
        lsum[r] += s;
      }

      // O += P V
      bf16x8 pf[2];
      #pragma unroll
      for (int ks = 0; ks < 2; ++ks){
        int pbyte = (lrow*128 + (ks*32 + lhi*8)*2) ^ (((lrow ^ (lrow >> 3)) & 7) << 4);
        pf[ks] = *(const bf16x8*)((char*)Pw + pbyte);
      }
      #pragma unroll
      for (int df = 0; df < 8; ++df){
        f32x4 a = o[df];
        #pragma unroll
        for (int ks = 0; ks < 2; ++ks){
          int d = df*16 + lrow;
          int vbyte = (d*128 + (ks*32 + lhi*8)*2) ^ (((d ^ (d >> 3)) & 7) << 4);
          bf16x8 vf = *(const bf16x8*)(Vc + vbyte);
          a = __builtin_amdgcn_mfma_f32_16x16x32_bf16(pf[ks], vf, a, 0, 0, 0);
        }
        o[df] = a;
      }
    }
    __syncthreads();
  }

  // normalize and store context (bf16)
  #pragma unroll
  for (int r = 0; r < 4; ++r){
    float inv = 1.f / lsum[r];
    size_t base = (size_t)(b*SS + q0 + w*16 + lhi*4 + r) * 4096 + h*HD + lrow;
    #pragma unroll
    for (int df = 0; df < 8; ++df)
      ctx[base + df*16] = f2bf(o[df][r] * inv);
  }
}

// ---- workspace layout (bytes) ----
#define O_HSB   ((size_t)0)            // 33,554,432  hs bf16 [4096][4096]
#define O_WQT   ((size_t)33554432)     // 33,554,432  WqT bf16 [4096][4096]; later reused for VT (8MB)
#define O_WKT   ((size_t)67108864)     //  8,388,608  WkT bf16 [1024][4096]
#define O_WVT   ((size_t)75497472)     //  8,388,608  WvT bf16 [1024][4096]
#define O_WOT   ((size_t)83886080)     // 33,554,432  WoT bf16 [4096][4096]
#define O_Q     ((size_t)117440512)    // 33,554,432  Q bf16 [4096][4096]
#define O_K     ((size_t)150994944)    //  8,388,608  K bf16 [4096][1024]
#define O_V     ((size_t)159383552)    //  8,388,608  V bf16 [4096][1024]
#define O_CTX   ((size_t)167772160)    // 33,554,432  ctx bf16 [4096][4096]
#define WS_NEED ((size_t)201326592)

extern "C" void kernel_launch(void* const* d_in, const int* in_sizes, int n_in,
                              void* d_out, int out_size, void* d_ws, size_t ws_size,
                              hipStream_t stream){
  if (ws_size < WS_NEED) return;
  const float* hs = (const float*)d_in[0];
  const float* Wq = (const float*)d_in[1];
  const float* Wk = (const float*)d_in[2];
  const float* Wv = (const float*)d_in[3];
  const float* Wo = (const float*)d_in[4];
  char* ws = (char*)d_ws;
  unsigned short* hsb = (unsigned short*)(ws + O_HSB);
  unsigned short* WqT = (unsigned short*)(ws + O_WQT);
  unsigned short* WkT = (unsigned short*)(ws + O_WKT);
  unsigned short* WvT = (unsigned short*)(ws + O_WVT);
  unsigned short* WoT = (unsigned short*)(ws + O_WOT);
  unsigned short* Qb  = (unsigned short*)(ws + O_Q);
  unsigned short* Kb  = (unsigned short*)(ws + O_K);
  unsigned short* Vb  = (unsigned short*)(ws + O_V);
  unsigned short* ctxb= (unsigned short*)(ws + O_CTX);
  unsigned short* VTb = (unsigned short*)(ws + O_WQT);  // reuse WqT region after Q proj

  // hs -> bf16
  cvt_f32_bf16_k<<<dim3((NTOK*HIDDEN/8)/256), dim3(256), 0, stream>>>(hs, hsb, NTOK*HIDDEN/8);
  // weights -> transposed bf16 ([N][K])
  transpose_cvt_k<<<dim3(128,128), dim3(32,8), 0, stream>>>(Wq, WqT, 4096, 4096);
  transpose_cvt_k<<<dim3(32,128),  dim3(32,8), 0, stream>>>(Wk, WkT, 4096, 1024);
  transpose_cvt_k<<<dim3(32,128),  dim3(32,8), 0, stream>>>(Wv, WvT, 4096, 1024);
  transpose_cvt_k<<<dim3(128,128), dim3(32,8), 0, stream>>>(Wo, WoT, 4096, 4096);
  // projections (Q first: its weight buffer is recycled for VT)
  gemm_bt_k<unsigned short><<<dim3(32,32), dim3(256), 0, stream>>>(hsb, WqT, Qb, 4096, 4096, 4096);
  gemm_bt_k<unsigned short><<<dim3(8,32),  dim3(256), 0, stream>>>(hsb, WkT, Kb, 4096, 1024, 4096);
  gemm_bt_k<unsigned short><<<dim3(8,32),  dim3(256), 0, stream>>>(hsb, WvT, Vb, 4096, 1024, 4096);
  // V -> V^T ([b*1024+c][s])
  transpose_v_k<<<dim3(32,128), dim3(32,8), 0, stream>>>(Vb, VTb);
  // attention
  attn_k<<<dim3(1024), dim3(512), 0, stream>>>(Qb, Kb, VTb, ctxb);
  // output projection (fp32 out)
  gemm_bt_k<float><<<dim3(32,32), dim3(256), 0, stream>>>(ctxb, WoT, (float*)d_out, 4096, 4096, 4096);
}

// Round 4
// 638.838 us; speedup vs baseline: 2.1328x; 1.2827x over previous
//
#include <hip/hip_runtime.h>
#include <hip/hip_bf16.h>
#include <type_traits>
#include <cmath>

// ---- problem constants ----
#define HIDDEN 4096
#define NHEADS 32
#define NKV 8
#define HD 128
#define BB 2
#define SS 2048
#define NTOK (BB*SS)                  // 4096 tokens
#define ATTN_MULT 0.08838834764831845f

using bf16x8 = __attribute__((ext_vector_type(8))) short;
using f32x4  = __attribute__((ext_vector_type(4))) float;

using gas = __attribute__((address_space(1))) const void;
using las = __attribute__((address_space(3))) void;

__device__ __forceinline__ unsigned short f2bf(float f){
  unsigned int u = __builtin_bit_cast(unsigned int, f);
  u += 0x7fffu + ((u >> 16) & 1u);
  return (unsigned short)(u >> 16);
}

// ---- fp32 -> bf16 elementwise (8 el/thread) ----
__global__ void cvt_f32_bf16_k(const float* __restrict__ in, unsigned short* __restrict__ out, int n8){
  int i = blockIdx.x * blockDim.x + threadIdx.x;
  if (i >= n8) return;
  const float4* p = (const float4*)in + (size_t)i * 2;
  float4 a = p[0], b = p[1];
  bf16x8 o;
  o[0]=f2bf(a.x); o[1]=f2bf(a.y); o[2]=f2bf(a.z); o[3]=f2bf(a.w);
  o[4]=f2bf(b.x); o[5]=f2bf(b.y); o[6]=f2bf(b.z); o[7]=f2bf(b.w);
  ((bf16x8*)out)[i] = o;
}

// ---- W[K][N] fp32 -> WT[N][K] bf16 (tiled transpose) ----
__global__ void transpose_cvt_k(const float* __restrict__ W, unsigned short* __restrict__ WT, int K, int N){
  __shared__ float tile[32][33];
  int n0 = blockIdx.x * 32, k0 = blockIdx.y * 32;
  int tx = threadIdx.x, ty = threadIdx.y; // 32 x 8
  #pragma unroll
  for (int i = 0; i < 4; ++i)
    tile[ty*4+i][tx] = W[(size_t)(k0 + ty*4 + i) * N + n0 + tx];
  __syncthreads();
  #pragma unroll
  for (int i = 0; i < 4; ++i)
    WT[(size_t)(n0 + ty*4 + i) * K + k0 + tx] = f2bf(tile[tx][ty*4+i]);
}

// ---- bf16 KV[4096][2048] (V in cols 1024..2047) -> VT[(b*1024+c)][s] ----
__global__ void transpose_v_k(const unsigned short* __restrict__ in, unsigned short* __restrict__ out){
  __shared__ unsigned short tile[32][33];
  int c0 = blockIdx.x * 32, r0 = blockIdx.y * 32;
  int tx = threadIdx.x, ty = threadIdx.y; // 32 x 8
  #pragma unroll
  for (int i = 0; i < 4; ++i)
    tile[ty*4+i][tx] = in[(size_t)(r0 + ty*4 + i) * 2048 + 1024 + c0 + tx];
  __syncthreads();
  #pragma unroll
  for (int i = 0; i < 4; ++i){
    int c = c0 + ty*4 + i, r = r0 + tx;
    out[((size_t)((r >> 11) * 1024 + c)) * 2048 + (r & 2047)] = tile[tx][ty*4+i];
  }
}

// ---- bf16 GEMM: C[M][N] = A[M][K] * BT[N][K]^T, m97-style 128x128x32 ----
template<typename OutT>
__global__ __launch_bounds__(256, 3)
void gemm_bt_k(const unsigned short* __restrict__ A,
               const unsigned short* __restrict__ BT,
               OutT* __restrict__ C, int M, int N, int K){
  __shared__ __align__(16) unsigned short As[128*32];
  __shared__ __align__(16) unsigned short Bs[128*32];
  const int m0 = blockIdx.y * 128, n0 = blockIdx.x * 128;
  const int tid = threadIdx.x, w = tid >> 6, lane = tid & 63;
  const int wr = w >> 1, wc = w & 1;
  const int lrow = lane & 15, lk = (lane >> 4) * 8;
  const int arow = lane >> 2, acol = (lane & 3) * 8;   // staging: lane covers 8 el

  f32x4 acc[4][4] = {};

  for (int k0 = 0; k0 < K; k0 += 32){
    #pragma unroll
    for (int i = 0; i < 2; ++i){
      int chunk = w*2 + i;  // 0..7, each 512 el (16 rows x 32 k)
      const unsigned short* ga = A  + (size_t)(m0 + chunk*16 + arow) * K + k0 + acol;
      const unsigned short* gb = BT + (size_t)(n0 + chunk*16 + arow) * K + k0 + acol;
      __builtin_amdgcn_global_load_lds((gas*)ga, (las*)(As + chunk*512), 16, 0, 0);
      __builtin_amdgcn_global_load_lds((gas*)gb, (las*)(Bs + chunk*512), 16, 0, 0);
    }
    __syncthreads();
    bf16x8 af[4], bfr[4];
    #pragma unroll
    for (int m = 0; m < 4; ++m) af[m]  = *(const bf16x8*)&As[(wr*64 + m*16 + lrow)*32 + lk];
    #pragma unroll
    for (int n = 0; n < 4; ++n) bfr[n] = *(const bf16x8*)&Bs[(wc*64 + n*16 + lrow)*32 + lk];
    #pragma unroll
    for (int m = 0; m < 4; ++m)
      #pragma unroll
      for (int n = 0; n < 4; ++n)
        acc[m][n] = __builtin_amdgcn_mfma_f32_16x16x32_bf16(af[m], bfr[n], acc[m][n], 0, 0, 0);
    __syncthreads();
  }

  const int crow = (lane >> 4) * 4, ccol = lane & 15;
  #pragma unroll
  for (int m = 0; m < 4; ++m)
    #pragma unroll
    for (int n = 0; n < 4; ++n){
      size_t base = (size_t)(m0 + wr*64 + m*16 + crow) * N + n0 + wc*64 + n*16 + ccol;
      #pragma unroll
      for (int r = 0; r < 4; ++r){
        float v = acc[m][n][r];
        if constexpr (std::is_same<OutT, unsigned short>::value) C[base + (size_t)r*N] = f2bf(v);
        else                                                     C[base + (size_t)r*N] = v;
      }
    }
}

// ---- causal GQA attention, QBLK=256 (8 waves x 32 q-rows), KVBLK=64 ----
// p = exp(30*tanh(s/30) - 30) = exp(-60/(exp(s/15)+1)).
// Each wave owns 32 q-rows (2 16-row groups) -> every K/V LDS fragment feeds
// 2 MFMAs. P round-trips through a 32x32 half-buffer per wave.
__global__ __launch_bounds__(512, 2)
void attn_k(const unsigned short* __restrict__ Q,
            const unsigned short* __restrict__ KVp,
            const unsigned short* __restrict__ VTp,
            unsigned short* __restrict__ ctx){
  __shared__ __align__(16) unsigned short Ks[2][64*128];   // [kv][d], read-XOR (kv&7)<<4
  __shared__ __align__(16) unsigned short Vt[2][128*64];   // [d][kv], read-XOR ((d^(d>>3))&7)<<4
  __shared__ __align__(16) unsigned short Ps[8][32*32];    // per-wave [32 q][32 kv] half, XOR ((row>>2)&3)<<4

  // balanced XCD-chunked decode: each CU gets one heavy (qt=7-a) + one light (qt=a) block
  const int Wb = blockIdx.x;
  const int xcd = Wb & 7, s = Wb >> 3;           // s 0..63
  const int idx = s & 31, half = s >> 5;
  const int a = idx & 3;
  const int qt = half ? a : 7 - a;
  const int hs = (idx >> 2) & 3, gsub = (idx >> 4) & 1;
  const int group = xcd*2 + gsub;                 // 0..15 = b*8 + kvh
  const int b = group >> 3, kvh = group & 7;
  const int h = kvh*4 + hs;

  const int tid = threadIdx.x, w = tid >> 6, lane = tid & 63;
  const int q0 = qt * 256;
  const int nt = 4*qt + 4;
  const int lrow = lane & 15, lhi = lane >> 4;
  const int qwb = q0 + w*32;                      // wave's q base

  // Q fragments: 32 rows per wave (2 groups of 16)
  bf16x8 qf[2][4];
  {
    const unsigned short* qb = Q + (size_t)(b*SS + qwb + lrow) * 4096 + h*HD + lhi*8;
    #pragma unroll
    for (int qg = 0; qg < 2; ++qg)
      #pragma unroll
      for (int ks = 0; ks < 4; ++ks)
        qf[qg][ks] = *(const bf16x8*)(qb + (size_t)qg*16*4096 + ks*32);
  }

  f32x4 o[8][2] = {};
  float psum[8] = {};

  const unsigned short* Kbh  = KVp + (size_t)b * SS * 2048 + kvh * HD;
  const unsigned short* VTbh = VTp + ((size_t)b * 1024 + kvh * HD) * SS;

  auto STAGE = [&](int db, int t){
    #pragma unroll
    for (int it = 0; it < 2; ++it){
      int cbase = it*512 + w*64;       // wave-uniform
      int c = cbase + lane;            // chunk 0..1023 (16B each)
      int kkv = c >> 4, kc = c & 15;
      const unsigned short* gk = Kbh + (size_t)(t*64 + kkv) * 2048 + ((kc ^ (kkv & 7)) << 3);
      __builtin_amdgcn_global_load_lds((gas*)gk, (las*)(&Ks[db][0] + cbase*8), 16, 0, 0);
      int vd = c >> 3, vc = c & 7;
      const unsigned short* gv = VTbh + (size_t)vd * SS + t*64 + ((vc ^ ((vd ^ (vd >> 3)) & 7)) << 3);
      __builtin_amdgcn_global_load_lds((gas*)gv, (las*)(&Vt[db][0] + cbase*8), 16, 0, 0);
    }
  };

  STAGE(0, 0);
  __syncthreads();

  for (int t = 0; t < nt; ++t){
    const int db = t & 1;
    if (t + 1 < nt) STAGE(db ^ 1, t + 1);

    if (t*64 <= qwb + 31){          // wave has at least one unmasked row
      const char* Kc = (const char*)&Ks[db][0];
      const char* Vc = (const char*)&Vt[db][0];
      unsigned short* Pw = &Ps[w][0];

      #pragma unroll
      for (int hh = 0; hh < 2; ++hh){
        // S for kv-cols hh*32..hh*32+31 (two cf groups), softmax, P write
        #pragma unroll
        for (int cc = 0; cc < 2; ++cc){
          const int cf = hh*2 + cc;
          const int row = cf*16 + lrow;
          bf16x8 kf[4];
          #pragma unroll
          for (int ks = 0; ks < 4; ++ks){
            int kbyte = (row*256 + (ks*32 + lhi*8)*2) ^ ((row & 7) << 4);
            kf[ks] = *(const bf16x8*)(Kc + kbyte);
          }
          f32x4 s0 = {0.f,0.f,0.f,0.f}, s1 = {0.f,0.f,0.f,0.f};
          #pragma unroll
          for (int ks = 0; ks < 4; ++ks){
            s0 = __builtin_amdgcn_mfma_f32_16x16x32_bf16(qf[0][ks], kf[ks], s0, 0, 0, 0);
            s1 = __builtin_amdgcn_mfma_f32_16x16x32_bf16(qf[1][ks], kf[ks], s1, 0, 0, 0);
          }
          const int kvg = t*64 + cf*16 + lrow;
          const int colh = cc*16 + lrow;
          #pragma unroll
          for (int qg = 0; qg < 2; ++qg){
            #pragma unroll
            for (int r = 0; r < 4; ++r){
              float sc = (qg ? s1[r] : s0[r]) * ATTN_MULT;
              float e  = __expf(sc * (2.f/30.f));
              float ex = -60.f * __builtin_amdgcn_rcpf(e + 1.f);
              int qglob = qwb + qg*16 + lhi*4 + r;
              float p = (kvg <= qglob) ? __expf(ex) : 0.f;
              psum[qg*4 + r] += p;
              int prow = qg*16 + lhi*4 + r;
              int pbyte = prow*64 + ((colh*2) ^ (((prow >> 2) & 3) << 4));
              *(unsigned short*)((char*)Pw + pbyte) = f2bf(p);
            }
          }
        }
        // O += P_half * V_half   (k = 32)
        bf16x8 pf[2];
        #pragma unroll
        for (int qg = 0; qg < 2; ++qg){
          int prow = qg*16 + lrow;
          int pbyte = prow*64 + ((lhi*16) ^ (((prow >> 2) & 3) << 4));
          pf[qg] = *(const bf16x8*)((char*)Pw + pbyte);
        }
        #pragma unroll
        for (int df = 0; df < 8; ++df){
          int d = df*16 + lrow;
          int vbyte = (d*128 + (hh*32 + lhi*8)*2) ^ (((d ^ (d >> 3)) & 7) << 4);
          bf16x8 vf = *(const bf16x8*)(Vc + vbyte);
          o[df][0] = __builtin_amdgcn_mfma_f32_16x16x32_bf16(pf[0], vf, o[df][0], 0, 0, 0);
          o[df][1] = __builtin_amdgcn_mfma_f32_16x16x32_bf16(pf[1], vf, o[df][1], 0, 0, 0);
        }
      }
    }
    __syncthreads();
  }

  // reduce row sums over the 16 kv-lanes, normalize, store
  #pragma unroll
  for (int qg = 0; qg < 2; ++qg){
    #pragma unroll
    for (int r = 0; r < 4; ++r){
      float sum = psum[qg*4 + r];
      sum += __shfl_xor(sum, 1);
      sum += __shfl_xor(sum, 2);
      sum += __shfl_xor(sum, 4);
      sum += __shfl_xor(sum, 8);
      float inv = 1.f / sum;
      size_t base = (size_t)(b*SS + qwb + qg*16 + lhi*4 + r) * 4096 + h*HD + lrow;
      #pragma unroll
      for (int df = 0; df < 8; ++df)
        ctx[base + df*16] = f2bf(o[df][qg][r] * inv);
    }
  }
}

// ---- workspace layout (bytes) ----
#define O_HSB   ((size_t)0)            // 33,554,432  hs bf16 [4096][4096]
#define O_WQT   ((size_t)33554432)     // 33,554,432  WqT bf16; later reused for VT (8MB)
#define O_WKT   ((size_t)67108864)     //  8,388,608  WkT bf16 [1024][4096]
#define O_WVT   ((size_t)75497472)     //  8,388,608  WvT bf16 [1024][4096] (contiguous after WkT)
#define O_WOT   ((size_t)83886080)     // 33,554,432  WoT bf16 [4096][4096]
#define O_Q     ((size_t)117440512)    // 33,554,432  Q bf16 [4096][4096]
#define O_KV    ((size_t)150994944)    // 16,777,216  KV bf16 [4096][2048] (K|V)
#define O_CTX   ((size_t)167772160)    // 33,554,432  ctx bf16 [4096][4096]
#define WS_NEED ((size_t)201326592)

extern "C" void kernel_launch(void* const* d_in, const int* in_sizes, int n_in,
                              void* d_out, int out_size, void* d_ws, size_t ws_size,
                              hipStream_t stream){
  if (ws_size < WS_NEED) return;
  const float* hs = (const float*)d_in[0];
  const float* Wq = (const float*)d_in[1];
  const float* Wk = (const float*)d_in[2];
  const float* Wv = (const float*)d_in[3];
  const float* Wo = (const float*)d_in[4];
  char* ws = (char*)d_ws;
  unsigned short* hsb = (unsigned short*)(ws + O_HSB);
  unsigned short* WqT = (unsigned short*)(ws + O_WQT);
  unsigned short* WkT = (unsigned short*)(ws + O_WKT);
  unsigned short* WvT = (unsigned short*)(ws + O_WVT);
  unsigned short* WoT = (unsigned short*)(ws + O_WOT);
  unsigned short* Qb  = (unsigned short*)(ws + O_Q);
  unsigned short* KVb = (unsigned short*)(ws + O_KV);
  unsigned short* ctxb= (unsigned short*)(ws + O_CTX);
  unsigned short* VTb = (unsigned short*)(ws + O_WQT);  // reuse WqT region after Q proj

  // hs -> bf16
  cvt_f32_bf16_k<<<dim3((NTOK*HIDDEN/8)/256), dim3(256), 0, stream>>>(hs, hsb, NTOK*HIDDEN/8);
  // weights -> transposed bf16 ([N][K]); WkT/WvT contiguous -> one [2048][4096]
  transpose_cvt_k<<<dim3(128,128), dim3(32,8), 0, stream>>>(Wq, WqT, 4096, 4096);
  transpose_cvt_k<<<dim3(32,128),  dim3(32,8), 0, stream>>>(Wk, WkT, 4096, 1024);
  transpose_cvt_k<<<dim3(32,128),  dim3(32,8), 0, stream>>>(Wv, WvT, 4096, 1024);
  transpose_cvt_k<<<dim3(128,128), dim3(32,8), 0, stream>>>(Wo, WoT, 4096, 4096);
  // projections (Q first: its weight buffer is recycled for VT)
  gemm_bt_k<unsigned short><<<dim3(32,32), dim3(256), 0, stream>>>(hsb, WqT, Qb, 4096, 4096, 4096);
  gemm_bt_k<unsigned short><<<dim3(16,32), dim3(256), 0, stream>>>(hsb, WkT, KVb, 4096, 2048, 4096);
  // V (KV cols 1024..2047) -> V^T [(b*1024+c)][s]
  transpose_v_k<<<dim3(32,128), dim3(32,8), 0, stream>>>(KVb, VTb);
  // attention
  attn_k<<<dim3(512), dim3(512), 0, stream>>>(Qb, KVb, VTb, ctxb);
  // output projection (fp32 out)
  gemm_bt_k<float><<<dim3(32,32), dim3(256), 0, stream>>>(ctxb, WoT, (float*)d_out, 4096, 4096, 4096);
}